// Round 2
// baseline (796.975 us; speedup 1.0000x reference)
//
#include <hip/hip_runtime.h>

typedef unsigned short u16;
typedef __attribute__((ext_vector_type(8))) short short8;
typedef __attribute__((ext_vector_type(4))) float f32x4;

#define DEV static __device__ __forceinline__

#define B_  4
#define S_  4096
#define D_  1024
#define E_  8
#define EPSf 1e-6f

DEV u16 f2bf(float f){
  unsigned u = __float_as_uint(f);
  u = (u + 0x7fffu + ((u >> 16) & 1u)) >> 16;
  return (u16)u;
}
DEV float bf2f(u16 v){ return __uint_as_float(((unsigned)v) << 16); }
DEV float softplusf_(float x){ return fmaxf(x, 0.f) + log1pf(__expf(-fabsf(x))); }
DEV float logaddexpf_(float a, float b){
  float m = fmaxf(a, b);
  return m + log1pf(__expf(fminf(a, b) - m));
}
DEV float log_gf(float x){ return x >= 0.f ? __logf(x + 0.5f) : -softplusf_(-x); }

DEV void gload_lds16(const void* g, void* l){
  __builtin_amdgcn_global_load_lds((const __attribute__((address_space(1))) unsigned int*)g,
                                   (__attribute__((address_space(3))) unsigned int*)l, 16, 0, 0);
}

// ---------------- kernel 1: RMSNorm -> x (bf16) ----------------
__global__ __launch_bounds__(256) void k_rmsnorm(const float* __restrict__ in,
                                                 const float* __restrict__ nw,
                                                 u16* __restrict__ x){
  int row = blockIdx.x;                       // b*S + s
  int t = threadIdx.x;
  const float4* rp = (const float4*)(in + (size_t)row * D_);
  float4 v = rp[t];
  float ss = v.x*v.x + v.y*v.y + v.z*v.z + v.w*v.w;
  #pragma unroll
  for(int o = 32; o; o >>= 1) ss += __shfl_down(ss, o);
  __shared__ float red[4];
  if((t & 63) == 0) red[t >> 6] = ss;
  __syncthreads();
  float rs = rsqrtf((red[0]+red[1]+red[2]+red[3]) * (1.f/D_) + EPSf);
  float4 w = ((const float4*)nw)[t];
  ushort4 o4;
  o4.x = f2bf(v.x*rs*w.x); o4.y = f2bf(v.y*rs*w.y);
  o4.z = f2bf(v.z*rs*w.z); o4.w = f2bf(v.w*rs*w.w);
  ((ushort4*)x)[(size_t)row * (D_/4) + t] = o4;
}

// ---------------- kernel 2: partial column sums of x over S ----------------
__global__ __launch_bounds__(256) void k_colsum(const u16* __restrict__ x, float* __restrict__ part){
  int blk = blockIdx.x;                       // b*64 + c*4 + dchunk
  int dc = blk & 3, c = (blk >> 2) & 15, b = blk >> 6;
  int d = dc*256 + threadIdx.x;
  const u16* p = x + ((size_t)b*S_ + (size_t)c*256) * D_ + d;
  float s = 0.f;
  #pragma unroll 8
  for(int i = 0; i < 256; ++i) s += bf2f(p[(size_t)i * D_]);
  part[((b << 4) + c) * D_ + d] = s;
}

__global__ __launch_bounds__(256) void k_meanx(const float* __restrict__ part, float* __restrict__ meanx){
  int idx = blockIdx.x * 256 + threadIdx.x;   // b*D + d
  int b = idx >> 10, d = idx & 1023;
  float s = 0.f;
  #pragma unroll
  for(int c = 0; c < 16; ++c) s += part[((b << 4) + c) * D_ + d];
  meanx[idx] = s * (1.f / S_);
}

// ---------------- kernel 3: router logits + softmax ----------------
__global__ __launch_bounds__(256) void k_router(const float* __restrict__ meanx,
                                                const float* __restrict__ rw,
                                                float* __restrict__ probs){
  int t = threadIdx.x; int b = t >> 6; int l = t & 63;
  int e = l & 7, g = l >> 3;
  float acc = 0.f;
  for(int i = 0; i < 128; ++i){
    int d = g*128 + i;
    acc += meanx[b*D_ + d] * rw[d*E_ + e];
  }
  acc += __shfl_down(acc, 32);
  acc += __shfl_down(acc, 16);
  acc += __shfl_down(acc, 8);
  float m = acc;
  #pragma unroll
  for(int o = 1; o < 8; o <<= 1) m = fmaxf(m, __shfl_xor(m, o));
  float ex = __expf(acc - m);
  float s = ex;
  #pragma unroll
  for(int o = 1; o < 8; o <<= 1) s += __shfl_xor(s, o);
  if(l < 8) probs[b*E_ + l] = ex / s;
}

// ---------------- kernel 4: expert-mix + transpose -> Wt[b][n][d] bf16 ----------------
template<int NN>
__global__ __launch_bounds__(256) void k_mix(const float* __restrict__ w,
                                             const float* __restrict__ probs,
                                             u16* __restrict__ wt){
  __shared__ float pr[32];
  __shared__ float lds[32][33];
  int t = threadIdx.x;
  if(t < 32) pr[t] = probs[t];
  int tiles_n = NN / 32;
  int td = blockIdx.x / tiles_n, tn = blockIdx.x % tiles_n;
  int dl = t >> 3, n4 = (t & 7) * 4;
  float4 acc[4];
  #pragma unroll
  for(int b = 0; b < 4; ++b) acc[b] = make_float4(0.f, 0.f, 0.f, 0.f);
  __syncthreads();
  const float* base = w + (size_t)(td*32 + dl) * NN + tn*32 + n4;
  #pragma unroll
  for(int e = 0; e < 8; ++e){
    float4 v = *(const float4*)(base + (size_t)e * D_ * NN);
    #pragma unroll
    for(int b = 0; b < 4; ++b){
      float pp = pr[b*8 + e];
      acc[b].x += pp*v.x; acc[b].y += pp*v.y; acc[b].z += pp*v.z; acc[b].w += pp*v.w;
    }
  }
  int kl = t >> 3, d4 = (t & 7) * 4;
  #pragma unroll
  for(int b = 0; b < 4; ++b){
    __syncthreads();
    lds[dl][n4] = acc[b].x; lds[dl][n4+1] = acc[b].y;
    lds[dl][n4+2] = acc[b].z; lds[dl][n4+3] = acc[b].w;
    __syncthreads();
    ushort4 o;
    o.x = f2bf(lds[d4][kl]);   o.y = f2bf(lds[d4+1][kl]);
    o.z = f2bf(lds[d4+2][kl]); o.w = f2bf(lds[d4+3][kl]);
    *(ushort4*)(wt + ((size_t)b*NN + tn*32 + kl) * D_ + td*32 + d4) = o;
  }
}

// ---------------- GEMM: C[M,N] = A[M,K] * Bt[N,K]^T  (bf16 in, MFMA f32 acc) ----------------
template<bool FUSE>
__global__ __launch_bounds__(256) void k_gemm(const u16* __restrict__ Ag, const u16* __restrict__ Btg,
                                              void* __restrict__ Cg, const float* __restrict__ addg,
                                              int Mtiles, int Ntiles, int Kelems, int Nstride)
{
  __shared__ __align__(16) char lds[32768];
  char* As = lds;
  char* Bs = lds + 16384;
  int per_b = Mtiles * Ntiles;
  int b  = blockIdx.x / per_b;
  int rr = blockIdx.x % per_b;
  int mt = rr / Ntiles, nt = rr % Ntiles;
  const char* Abase = (const char*)(Ag + (size_t)(b * Mtiles + mt) * 128 * Kelems);
  const char* Bbase = (const char*)(Btg + (size_t)(b * Ntiles + nt) * 128 * Kelems);
  int t = threadIdx.x;
  int l = t & 63;
  int w = t >> 6, wr = w >> 1, wc = w & 1;
  f32x4 acc[4][4] = {};
  int ktiles = Kelems >> 6;
  size_t rowstride = (size_t)Kelems * 2;
  for(int kt = 0; kt < ktiles; ++kt){
    if(kt) __syncthreads();
    #pragma unroll
    for(int i = 0; i < 4; ++i){
      int o   = (i*256 + t) * 16;                 // linear LDS byte offset
      int row = o >> 7;                           // 128B per row (64 bf16)
      int kb  = (o & 127) ^ ((row & 7) << 4);     // inverse-swizzled global chunk
      size_t goff = (size_t)row * rowstride + (size_t)(kt*128 + kb);
      int lo  = (i*256 + (t & ~63)) * 16;         // wave-uniform LDS base
      gload_lds16(Abase + goff, As + lo);
      gload_lds16(Bbase + goff, Bs + lo);
    }
    __syncthreads();
    #pragma unroll
    for(int kk = 0; kk < 2; ++kk){
      short8 af[4], bfr[4];
      int lk = kk*64 + ((l >> 4) << 4);
      #pragma unroll
      for(int mi = 0; mi < 4; ++mi){
        int row = wr*64 + mi*16 + (l & 15);
        af[mi] = *(const short8*)(As + row*128 + (lk ^ ((row & 7) << 4)));
      }
      #pragma unroll
      for(int ni = 0; ni < 4; ++ni){
        int row = wc*64 + ni*16 + (l & 15);
        bfr[ni] = *(const short8*)(Bs + row*128 + (lk ^ ((row & 7) << 4)));
      }
      #pragma unroll
      for(int mi = 0; mi < 4; ++mi)
        #pragma unroll
        for(int ni = 0; ni < 4; ++ni)
          acc[mi][ni] = __builtin_amdgcn_mfma_f32_16x16x32_bf16(af[mi], bfr[ni], acc[mi][ni], 0, 0, 0);
    }
  }
  int M = Mtiles * 128;
  #pragma unroll
  for(int mi = 0; mi < 4; ++mi){
    #pragma unroll
    for(int ni = 0; ni < 4; ++ni){
      int col = nt*128 + wc*64 + ni*16 + (l & 15);
      #pragma unroll
      for(int j = 0; j < 4; ++j){
        int rowg = mt*128 + wr*64 + mi*16 + ((l >> 4) << 2) + j;
        size_t idx = ((size_t)b * M + rowg) * (size_t)Nstride + col;
        float v = acc[mi][ni][j];
        if constexpr (FUSE) ((float*)Cg)[idx] = v + addg[idx];
        else                ((u16*)Cg)[idx]  = f2bf(v);
      }
    }
  }
}

// ---------------- scan phase 1: per-chunk (A,B) composition ----------------
__global__ __launch_bounds__(256) void k_scan1(const u16* __restrict__ hg,
                                               float* __restrict__ Aseg, float* __restrict__ Bseg){
  int blk = blockIdx.x;                       // b*256 + c*4 + dchunk
  int dc = blk & 3, c = (blk >> 2) & 63, b = blk >> 8;
  int d = dc*256 + threadIdx.x;
  const u16* p = hg + ((size_t)b*S_ + (size_t)c*64) * 2048 + d;
  float As = 0.f, Bs = -INFINITY;
  for(int i = 0; i < 64; ++i){
    float hid = bf2f(p[(size_t)i*2048]);
    float gt  = bf2f(p[(size_t)i*2048 + 1024]);
    float lc = -softplusf_(gt);
    float lv = -softplusf_(-gt) + log_gf(hid);
    As += lc;
    Bs = logaddexpf_(Bs + lc, lv);
  }
  int o = ((b << 6) + c) * D_ + d;
  Aseg[o] = As; Bseg[o] = Bs;
}

// ---------------- scan phase 2: prefix over chunks ----------------
__global__ __launch_bounds__(256) void k_scan2(const float* __restrict__ Aseg, const float* __restrict__ Bseg,
                                               const float* __restrict__ cs, float* __restrict__ pref){
  int idx = blockIdx.x * 256 + threadIdx.x;   // b*D + d
  int b = idx >> 10, d = idx & 1023;
  float lh = __logf(cs[idx]);
  for(int c = 0; c < 64; ++c){
    int o = ((b << 6) + c) * D_ + d;
    pref[o] = lh;
    lh = logaddexpf_(Aseg[o] + lh, Bseg[o]);
  }
}

// ---------------- scan phase 3: replay chunks, emit h (bf16) + state ----------------
__global__ __launch_bounds__(256) void k_scan3(const u16* __restrict__ hg, const float* __restrict__ pref,
                                               u16* __restrict__ h, float* __restrict__ st,
                                               float* __restrict__ aux){
  int blk = blockIdx.x;
  int dc = blk & 3, c = (blk >> 2) & 63, b = blk >> 8;
  int d = dc*256 + threadIdx.x;
  const u16* p = hg + ((size_t)b*S_ + (size_t)c*64) * 2048 + d;
  float lh = pref[((b << 6) + c) * D_ + d];
  float hv = 0.f;
  for(int i = 0; i < 64; ++i){
    float hid = bf2f(p[(size_t)i*2048]);
    float gt  = bf2f(p[(size_t)i*2048 + 1024]);
    float lc = -softplusf_(gt);
    float lv = -softplusf_(-gt) + log_gf(hid);
    lh = logaddexpf_(lc + lh, lv);
    hv = __expf(lh);
    h[((size_t)b*S_ + (size_t)c*64 + i) * D_ + d] = f2bf(hv);
  }
  if(c == 63) st[b*D_ + d] = hv;
  if(blk == 0 && threadIdx.x == 0) aux[0] = 0.f;
}

extern "C" void kernel_launch(void* const* d_in, const int* in_sizes, int n_in,
                              void* d_out, int out_size, void* d_ws, size_t ws_size,
                              hipStream_t stream)
{
  const float* inputs = (const float*)d_in[0];
  // d_in[1] = attention_mask (all ones, unused by reference)
  const float* cstate = (const float*)d_in[2];
  const float* normw  = (const float*)d_in[3];
  const float* rw     = (const float*)d_in[4];
  const float* w_in   = (const float*)d_in[5];
  const float* w_out  = (const float*)d_in[6];
  float* out = (float*)d_out;

  char* ws = (char*)d_ws;
  const size_t off_x   = 0;
  const size_t off_hg  = off_x  + (size_t)B_*S_*D_*2;
  const size_t off_h   = off_hg + (size_t)B_*S_*2048*2;
  const size_t off_wi  = off_h  + (size_t)B_*S_*D_*2;
  const size_t off_wo  = off_wi + (size_t)B_*2048*D_*2;
  const size_t off_pt  = off_wo + (size_t)B_*D_*D_*2;
  const size_t off_mx  = off_pt + (size_t)B_*16*D_*4;
  const size_t off_pr  = off_mx + (size_t)B_*D_*4;
  const size_t off_As  = off_pr + 256;
  const size_t off_Bs  = off_As + (size_t)B_*64*D_*4;
  const size_t off_pf  = off_Bs + (size_t)B_*64*D_*4;

  u16* x    = (u16*)(ws + off_x);
  u16* hg   = (u16*)(ws + off_hg);
  u16* h    = (u16*)(ws + off_h);
  u16* wi_t = (u16*)(ws + off_wi);
  u16* wo_t = (u16*)(ws + off_wo);
  float* part  = (float*)(ws + off_pt);
  float* meanx = (float*)(ws + off_mx);
  float* probs = (float*)(ws + off_pr);
  float* Aseg  = (float*)(ws + off_As);
  float* Bseg  = (float*)(ws + off_Bs);
  float* pref  = (float*)(ws + off_pf);

  k_rmsnorm<<<B_*S_, 256, 0, stream>>>(inputs, normw, x);
  k_colsum <<<256, 256, 0, stream>>>(x, part);
  k_meanx  <<<16, 256, 0, stream>>>(part, meanx);
  k_router <<<1, 256, 0, stream>>>(meanx, rw, probs);
  k_mix<2048><<<(D_/32)*(2048/32), 256, 0, stream>>>(w_in, probs, wi_t);
  k_mix<1024><<<(D_/32)*(1024/32), 256, 0, stream>>>(w_out, probs, wo_t);
  k_gemm<false><<<B_*32*16, 256, 0, stream>>>(x, wi_t, hg, nullptr, 32, 16, 1024, 2048);
  k_scan1<<<B_*64*4, 256, 0, stream>>>(hg, Aseg, Bseg);
  k_scan2<<<16, 256, 0, stream>>>(Aseg, Bseg, cstate, pref);
  k_scan3<<<B_*64*4, 256, 0, stream>>>(hg, pref, h,
                                       out + (size_t)B_*S_*D_,
                                       out + (size_t)B_*S_*D_ + B_*D_);
  k_gemm<true><<<B_*32*8, 256, 0, stream>>>(h, wo_t, out, inputs, 32, 8, 1024, 1024);
}

// Round 4
// 464.160 us; speedup vs baseline: 1.7170x; 1.7170x over previous
//
#include <hip/hip_runtime.h>

typedef unsigned short u16;
typedef __attribute__((ext_vector_type(8))) short short8;
typedef __attribute__((ext_vector_type(4))) float f32x4;

#define DEV static __device__ __forceinline__

#define B_  4
#define S_  4096
#define D_  1024
#define E_  8
#define C_  128     // scan chunks
#define L_  32      // steps per chunk
#define EPSf 1e-6f

DEV u16 f2bf(float f){
  unsigned u = __float_as_uint(f);
  u = (u + 0x7fffu + ((u >> 16) & 1u)) >> 16;
  return (u16)u;
}
DEV float bf2f(u16 v){ return __uint_as_float(((unsigned)v) << 16); }
DEV float rcp_(float x){ return __builtin_amdgcn_rcpf(x); }

// a = sigmoid(-g) = exp(-softplus(g));  v = sigmoid(g) * g(x),
// g(x) = x>=0 ? x+0.5 : sigmoid(x)   (exact linear-space form of the reference)
DEV void av_(float hid, float gt, float& a, float& v){
  float e1 = __expf(-gt);
  float s  = rcp_(1.f + e1);          // sigmoid(g); e1=inf -> s=0, a=1, v=0 (correct limit)
  a = 1.f - s;
  float gx = hid >= 0.f ? hid + 0.5f : rcp_(1.f + __expf(-hid));
  v = s * gx;
}

DEV void gload_lds16(const void* g, void* l){
  __builtin_amdgcn_global_load_lds((const __attribute__((address_space(1))) unsigned int*)g,
                                   (__attribute__((address_space(3))) unsigned int*)l, 16, 0, 0);
}

// ---------------- kernel 1: RMSNorm -> x (bf16) ----------------
__global__ __launch_bounds__(256) void k_rmsnorm(const float* __restrict__ in,
                                                 const float* __restrict__ nw,
                                                 u16* __restrict__ x){
  int row = blockIdx.x;                       // b*S + s
  int t = threadIdx.x;
  const float4* rp = (const float4*)(in + (size_t)row * D_);
  float4 v = rp[t];
  float ss = v.x*v.x + v.y*v.y + v.z*v.z + v.w*v.w;
  #pragma unroll
  for(int o = 32; o; o >>= 1) ss += __shfl_down(ss, o);
  __shared__ float red[4];
  if((t & 63) == 0) red[t >> 6] = ss;
  __syncthreads();
  float rs = rsqrtf((red[0]+red[1]+red[2]+red[3]) * (1.f/D_) + EPSf);
  float4 w = ((const float4*)nw)[t];
  ushort4 o4;
  o4.x = f2bf(v.x*rs*w.x); o4.y = f2bf(v.y*rs*w.y);
  o4.z = f2bf(v.z*rs*w.z); o4.w = f2bf(v.w*rs*w.w);
  ((ushort4*)x)[(size_t)row * (D_/4) + t] = o4;
}

// ---------------- kernel 2: partial column sums of x over S ----------------
__global__ __launch_bounds__(256) void k_colsum(const u16* __restrict__ x, float* __restrict__ part){
  int blk = blockIdx.x;                       // b*64 + c*4 + dchunk
  int dc = blk & 3, c = (blk >> 2) & 15, b = blk >> 6;
  int d = dc*256 + threadIdx.x;
  const u16* p = x + ((size_t)b*S_ + (size_t)c*256) * D_ + d;
  float s = 0.f;
  #pragma unroll 8
  for(int i = 0; i < 256; ++i) s += bf2f(p[(size_t)i * D_]);
  part[((b << 4) + c) * D_ + d] = s;
}

__global__ __launch_bounds__(256) void k_meanx(const float* __restrict__ part, float* __restrict__ meanx){
  int idx = blockIdx.x * 256 + threadIdx.x;   // b*D + d
  int b = idx >> 10, d = idx & 1023;
  float s = 0.f;
  #pragma unroll
  for(int c = 0; c < 16; ++c) s += part[((b << 4) + c) * D_ + d];
  meanx[idx] = s * (1.f / S_);
}

// ---------------- kernel 3: router logits + softmax ----------------
__global__ __launch_bounds__(256) void k_router(const float* __restrict__ meanx,
                                                const float* __restrict__ rw,
                                                float* __restrict__ probs){
  int t = threadIdx.x; int b = t >> 6; int l = t & 63;
  int e = l & 7, g = l >> 3;
  float acc = 0.f;
  for(int i = 0; i < 128; ++i){
    int d = g*128 + i;
    acc += meanx[b*D_ + d] * rw[d*E_ + e];
  }
  acc += __shfl_down(acc, 32);
  acc += __shfl_down(acc, 16);
  acc += __shfl_down(acc, 8);
  float m = acc;
  #pragma unroll
  for(int o = 1; o < 8; o <<= 1) m = fmaxf(m, __shfl_xor(m, o));
  float ex = __expf(acc - m);
  float s = ex;
  #pragma unroll
  for(int o = 1; o < 8; o <<= 1) s += __shfl_xor(s, o);
  if(l < 8) probs[b*E_ + l] = ex / s;
}

// ---------------- kernel 4: expert-mix + transpose -> Wt[b][n][d] bf16 ----------------
template<int NN>
__global__ __launch_bounds__(256) void k_mix(const float* __restrict__ w,
                                             const float* __restrict__ probs,
                                             u16* __restrict__ wt){
  __shared__ float pr[32];
  __shared__ float lds[32][33];
  int t = threadIdx.x;
  if(t < 32) pr[t] = probs[t];
  int tiles_n = NN / 32;
  int td = blockIdx.x / tiles_n, tn = blockIdx.x % tiles_n;
  int dl = t >> 3, n4 = (t & 7) * 4;
  float4 acc[4];
  #pragma unroll
  for(int b = 0; b < 4; ++b) acc[b] = make_float4(0.f, 0.f, 0.f, 0.f);
  __syncthreads();
  const float* base = w + (size_t)(td*32 + dl) * NN + tn*32 + n4;
  #pragma unroll
  for(int e = 0; e < 8; ++e){
    float4 v = *(const float4*)(base + (size_t)e * D_ * NN);
    #pragma unroll
    for(int b = 0; b < 4; ++b){
      float pp = pr[b*8 + e];
      acc[b].x += pp*v.x; acc[b].y += pp*v.y; acc[b].z += pp*v.z; acc[b].w += pp*v.w;
    }
  }
  int kl = t >> 3, d4 = (t & 7) * 4;
  #pragma unroll
  for(int b = 0; b < 4; ++b){
    __syncthreads();
    lds[dl][n4] = acc[b].x; lds[dl][n4+1] = acc[b].y;
    lds[dl][n4+2] = acc[b].z; lds[dl][n4+3] = acc[b].w;
    __syncthreads();
    ushort4 o;
    o.x = f2bf(lds[d4][kl]);   o.y = f2bf(lds[d4+1][kl]);
    o.z = f2bf(lds[d4+2][kl]); o.w = f2bf(lds[d4+3][kl]);
    *(ushort4*)(wt + ((size_t)b*NN + tn*32 + kl) * D_ + td*32 + d4) = o;
  }
}

// ---------------- GEMM: C[M,N] = A[M,K] * Bt[N,K]^T  (bf16 in, MFMA f32 acc) ----------------
template<bool FUSE>
__global__ __launch_bounds__(256) void k_gemm(const u16* __restrict__ Ag, const u16* __restrict__ Btg,
                                              void* __restrict__ Cg, const float* __restrict__ addg,
                                              int Mtiles, int Ntiles, int Kelems, int Nstride)
{
  __shared__ __align__(16) char lds[32768];
  char* As = lds;
  char* Bs = lds + 16384;
  int per_b = Mtiles * Ntiles;
  int b  = blockIdx.x / per_b;
  int rr = blockIdx.x % per_b;
  int mt = rr / Ntiles, nt = rr % Ntiles;
  const char* Abase = (const char*)(Ag + (size_t)(b * Mtiles + mt) * 128 * Kelems);
  const char* Bbase = (const char*)(Btg + (size_t)(b * Ntiles + nt) * 128 * Kelems);
  int t = threadIdx.x;
  int l = t & 63;
  int w = t >> 6, wr = w >> 1, wc = w & 1;
  f32x4 acc[4][4] = {};
  int ktiles = Kelems >> 6;
  size_t rowstride = (size_t)Kelems * 2;
  for(int kt = 0; kt < ktiles; ++kt){
    if(kt) __syncthreads();
    #pragma unroll
    for(int i = 0; i < 4; ++i){
      int o   = (i*256 + t) * 16;                 // linear LDS byte offset
      int row = o >> 7;                           // 128B per row (64 bf16)
      int kb  = (o & 127) ^ ((row & 7) << 4);     // inverse-swizzled global chunk
      size_t goff = (size_t)row * rowstride + (size_t)(kt*128 + kb);
      int lo  = (i*256 + (t & ~63)) * 16;         // wave-uniform LDS base
      gload_lds16(Abase + goff, As + lo);
      gload_lds16(Bbase + goff, Bs + lo);
    }
    __syncthreads();
    #pragma unroll
    for(int kk = 0; kk < 2; ++kk){
      short8 af[4], bfr[4];
      int lk = kk*64 + ((l >> 4) << 4);
      #pragma unroll
      for(int mi = 0; mi < 4; ++mi){
        int row = wr*64 + mi*16 + (l & 15);
        af[mi] = *(const short8*)(As + row*128 + (lk ^ ((row & 7) << 4)));
      }
      #pragma unroll
      for(int ni = 0; ni < 4; ++ni){
        int row = wc*64 + ni*16 + (l & 15);
        bfr[ni] = *(const short8*)(Bs + row*128 + (lk ^ ((row & 7) << 4)));
      }
      #pragma unroll
      for(int mi = 0; mi < 4; ++mi)
        #pragma unroll
        for(int ni = 0; ni < 4; ++ni)
          acc[mi][ni] = __builtin_amdgcn_mfma_f32_16x16x32_bf16(af[mi], bfr[ni], acc[mi][ni], 0, 0, 0);
    }
  }
  int M = Mtiles * 128;
  #pragma unroll
  for(int mi = 0; mi < 4; ++mi){
    #pragma unroll
    for(int ni = 0; ni < 4; ++ni){
      int col = nt*128 + wc*64 + ni*16 + (l & 15);
      #pragma unroll
      for(int j = 0; j < 4; ++j){
        int rowg = mt*128 + wr*64 + mi*16 + ((l >> 4) << 2) + j;
        size_t idx = ((size_t)b * M + rowg) * (size_t)Nstride + col;
        float v = acc[mi][ni][j];
        if constexpr (FUSE) ((float*)Cg)[idx] = v + addg[idx];
        else                ((u16*)Cg)[idx]  = f2bf(v);
      }
    }
  }
}

// ---------------- scan phase 1: per-chunk (A,B) composition, linear space ----------------
__global__ __launch_bounds__(256) void k_scan1(const u16* __restrict__ hg,
                                               float* __restrict__ Aseg, float* __restrict__ Bseg){
  int blk = blockIdx.x;                       // b*(C_*2) + c*2 + dchunk
  int dc = blk & 1, c = (blk >> 1) & (C_-1), b = blk >> 8;
  int d0 = dc*512 + threadIdx.x*2;
  const u16* p = hg + ((size_t)b*S_ + (size_t)c*L_) * 2048 + d0;
  float A0 = 1.f, A1 = 1.f, Bv0 = 0.f, Bv1 = 0.f;
  #pragma unroll 8
  for(int i = 0; i < L_; ++i){
    unsigned hv = *(const unsigned*)(p + (size_t)i*2048);
    unsigned gv = *(const unsigned*)(p + (size_t)i*2048 + 1024);
    float a, v;
    av_(bf2f(hv & 0xffff), bf2f(gv & 0xffff), a, v);
    A0 *= a; Bv0 = a*Bv0 + v;
    av_(bf2f(hv >> 16), bf2f(gv >> 16), a, v);
    A1 *= a; Bv1 = a*Bv1 + v;
  }
  size_t o = ((size_t)(b*C_ + c)) * D_ + d0;
  *(float2*)(Aseg + o) = make_float2(A0, A1);
  *(float2*)(Bseg + o) = make_float2(Bv0, Bv1);
}

// ---------------- scan phase 2: prefix over chunks (linear) ----------------
__global__ __launch_bounds__(256) void k_scan2(const float* __restrict__ Aseg, const float* __restrict__ Bseg,
                                               const float* __restrict__ cs, float* __restrict__ pref){
  int idx = blockIdx.x * 256 + threadIdx.x;   // b*D + d
  int b = idx >> 10, d = idx & 1023;
  float h0 = cs[idx];
  for(int c = 0; c < C_; ++c){
    size_t o = ((size_t)(b*C_ + c)) * D_ + d;
    pref[o] = h0;
    h0 = Aseg[o]*h0 + Bseg[o];
  }
}

// ---------------- scan phase 3: replay chunks (linear), emit h (bf16) + state ----------------
__global__ __launch_bounds__(256) void k_scan3(const u16* __restrict__ hg, const float* __restrict__ pref,
                                               u16* __restrict__ h, float* __restrict__ st,
                                               float* __restrict__ aux){
  int blk = blockIdx.x;
  int dc = blk & 1, c = (blk >> 1) & (C_-1), b = blk >> 8;
  int d0 = dc*512 + threadIdx.x*2;
  const u16* p = hg + ((size_t)b*S_ + (size_t)c*L_) * 2048 + d0;
  size_t o = ((size_t)(b*C_ + c)) * D_ + d0;
  float2 hp = *(const float2*)(pref + o);
  float h0 = hp.x, h1 = hp.y;
  #pragma unroll 8
  for(int i = 0; i < L_; ++i){
    unsigned hv = *(const unsigned*)(p + (size_t)i*2048);
    unsigned gv = *(const unsigned*)(p + (size_t)i*2048 + 1024);
    float a, v;
    av_(bf2f(hv & 0xffff), bf2f(gv & 0xffff), a, v);
    h0 = a*h0 + v;
    av_(bf2f(hv >> 16), bf2f(gv >> 16), a, v);
    h1 = a*h1 + v;
    unsigned ov = (unsigned)f2bf(h0) | ((unsigned)f2bf(h1) << 16);
    *(unsigned*)(h + ((size_t)b*S_ + (size_t)c*L_ + i) * D_ + d0) = ov;
  }
  if(c == C_-1) *(float2*)(st + b*D_ + d0) = make_float2(h0, h1);
  if(blk == 0 && threadIdx.x == 0) aux[0] = 0.f;
}

extern "C" void kernel_launch(void* const* d_in, const int* in_sizes, int n_in,
                              void* d_out, int out_size, void* d_ws, size_t ws_size,
                              hipStream_t stream)
{
  const float* inputs = (const float*)d_in[0];
  // d_in[1] = attention_mask (all ones, unused by reference)
  const float* cstate = (const float*)d_in[2];
  const float* normw  = (const float*)d_in[3];
  const float* rw     = (const float*)d_in[4];
  const float* w_in   = (const float*)d_in[5];
  const float* w_out  = (const float*)d_in[6];
  float* out = (float*)d_out;

  char* ws = (char*)d_ws;
  const size_t off_x   = 0;
  const size_t off_hg  = off_x  + (size_t)B_*S_*D_*2;
  const size_t off_h   = off_hg + (size_t)B_*S_*2048*2;
  const size_t off_wi  = off_h  + (size_t)B_*S_*D_*2;
  const size_t off_wo  = off_wi + (size_t)B_*2048*D_*2;
  const size_t off_pt  = off_wo + (size_t)B_*D_*D_*2;
  const size_t off_mx  = off_pt + (size_t)B_*16*D_*4;
  const size_t off_pr  = off_mx + (size_t)B_*D_*4;
  // scan scratch overlays x (x is dead after k_gemm<false>): 3 x 2MB << 33.5MB
  const size_t off_As  = off_x;
  const size_t off_Bs  = off_x + (size_t)B_*C_*D_*4;
  const size_t off_pf  = off_x + (size_t)2*B_*C_*D_*4;

  u16* x    = (u16*)(ws + off_x);
  u16* hg   = (u16*)(ws + off_hg);
  u16* h    = (u16*)(ws + off_h);
  u16* wi_t = (u16*)(ws + off_wi);
  u16* wo_t = (u16*)(ws + off_wo);
  float* part  = (float*)(ws + off_pt);
  float* meanx = (float*)(ws + off_mx);
  float* probs = (float*)(ws + off_pr);
  float* Aseg  = (float*)(ws + off_As);
  float* Bseg  = (float*)(ws + off_Bs);
  float* pref  = (float*)(ws + off_pf);

  k_rmsnorm<<<B_*S_, 256, 0, stream>>>(inputs, normw, x);
  k_colsum <<<256, 256, 0, stream>>>(x, part);
  k_meanx  <<<16, 256, 0, stream>>>(part, meanx);
  k_router <<<1, 256, 0, stream>>>(meanx, rw, probs);
  k_mix<2048><<<(D_/32)*(2048/32), 256, 0, stream>>>(w_in, probs, wi_t);
  k_mix<1024><<<(D_/32)*(1024/32), 256, 0, stream>>>(w_out, probs, wo_t);
  k_gemm<false><<<B_*32*16, 256, 0, stream>>>(x, wi_t, hg, nullptr, 32, 16, 1024, 2048);
  k_scan1<<<B_*C_*2, 256, 0, stream>>>(hg, Aseg, Bseg);
  k_scan2<<<16, 256, 0, stream>>>(Aseg, Bseg, cstate, pref);
  k_scan3<<<B_*C_*2, 256, 0, stream>>>(hg, pref, h,
                                       out + (size_t)B_*S_*D_,
                                       out + (size_t)B_*S_*D_ + B_*D_);
  k_gemm<true><<<B_*32*8, 256, 0, stream>>>(h, wo_t, out, inputs, 32, 8, 1024, 1024);
}